// Round 18
// baseline (333.633 us; speedup 1.0000x reference)
//
#include <hip/hip_runtime.h>
#include <math.h>

#define NB 8
#define HH 56
#define WWD 56
#define CC 256
#define PIX (NB*HH*WWD)   // 25088

typedef __attribute__((ext_vector_type(8))) short bf16x8;
typedef __attribute__((ext_vector_type(8))) unsigned short u16x8;
typedef __attribute__((ext_vector_type(4))) float f32x4;

// tanh-form GELU: x*sigmoid(1.5957691x + 0.0713555x^3); native exp/rcp.
__device__ __forceinline__ float gelu_fast(float x) {
    float z = x * fmaf(0.0713554668f, x*x, 1.5957691216f);
    return x * __fdividef(1.0f, 1.0f + __expf(-z));
}
__device__ __forceinline__ unsigned short f2bf(float f) {
    unsigned u = __float_as_uint(f);
    unsigned r = (u + 0x7fffu + ((u >> 16) & 1u)) >> 16;
    return (unsigned short)r;
}
__device__ __forceinline__ float bf2f(unsigned short b) {
    return __uint_as_float(((unsigned)b) << 16);
}
__device__ __forceinline__ void gl_lds16(const void* g, void* l) {
    __builtin_amdgcn_global_load_lds(
        (const __attribute__((address_space(1))) void*)g,
        (__attribute__((address_space(3))) void*)l, 16, 0, 0);
}
__device__ __forceinline__ void wave_reduce2(float& s, float& sq) {
    #pragma unroll
    for (int o = 32; o >= 1; o >>= 1) {
        s  += __shfl_xor(s, o);
        sq += __shfl_xor(sq, o);
    }
}

// ---- one prep kernel: weight transposes (fp32 -> bf16 N-major) + dwconv wt ----
__global__ __launch_bounds__(256) void prep_kernel(
    const float* __restrict__ inw, const float* __restrict__ offw,
    const float* __restrict__ offb, const float* __restrict__ mskw,
    const float* __restrict__ mskb, const float* __restrict__ outw,
    const float* __restrict__ f1w, const float* __restrict__ f2w,
    const float* __restrict__ dww,
    unsigned short* __restrict__ bt_in, unsigned short* __restrict__ bt_om,
    unsigned short* __restrict__ bt_out, unsigned short* __restrict__ bt_fc1,
    unsigned short* __restrict__ bt_fc2, float* __restrict__ wt9,
    float* __restrict__ bias_om)
{
    int i = blockIdx.x * 256 + threadIdx.x;
    if (i < 65536) {
        int n = i >> 8, k = i & 255;
        bt_in[i] = f2bf(inw[(size_t)k*256 + n]);
    } else if (i < 196608) {
        int j = i - 65536;
        int n = j >> 8, k = j & 255;
        float v = (n < 288) ? offw[(size_t)k*288 + n]
                : (n < 432) ? mskw[(size_t)k*144 + (n-288)] : 0.f;
        bt_om[j] = f2bf(v);
    } else if (i < 262144) {
        int j = i - 196608;
        int n = j >> 8, k = j & 255;
        bt_out[j] = f2bf(outw[(size_t)k*256 + n]);
    } else if (i < 524288) {
        int j = i - 262144;
        int n = j >> 8, k = j & 255;
        bt_fc1[j] = f2bf(f1w[(size_t)k*1024 + n]);
    } else if (i < 786432) {
        int j = i - 524288;
        int n = j >> 10, k = j & 1023;
        bt_fc2[j] = f2bf(f2w[(size_t)k*256 + n]);
    } else if (i < 788736) {
        int j = i - 786432;
        int t = j >> 8, c = j & 255;
        wt9[j] = dww[(size_t)c*9 + t];
    } else if (i < 789248) {
        int j = i - 788736;
        bias_om[j] = (j < 288) ? offb[j] : (j < 432) ? mskb[j-288] : 0.f;
    }
}

// LayerNorm over C=256, fp32 in -> bf16 out. One wave/pixel.
__global__ __launch_bounds__(256) void ln_bf_kernel(
    const float* __restrict__ in, const float* __restrict__ g,
    const float* __restrict__ b, unsigned short* __restrict__ out)
{
    int wave = threadIdx.x >> 6, lane = threadIdx.x & 63;
    int pix = blockIdx.x * 4 + wave;
    int c0 = lane * 4;
    float4 v = *reinterpret_cast<const float4*>(&in[(size_t)pix * CC + c0]);
    float s = v.x + v.y + v.z + v.w;
    float sq = v.x*v.x + v.y*v.y + v.z*v.z + v.w*v.w;
    wave_reduce2(s, sq);
    float mu = s * (1.0f/256.0f);
    float var = sq * (1.0f/256.0f) - mu*mu;
    float rs = rsqrtf(var + 1e-6f);
    float4 gv = *reinterpret_cast<const float4*>(&g[c0]);
    float4 bv = *reinterpret_cast<const float4*>(&b[c0]);
    ushort4 o;
    o.x = f2bf((v.x-mu)*rs*gv.x + bv.x);
    o.y = f2bf((v.y-mu)*rs*gv.y + bv.y);
    o.z = f2bf((v.z-mu)*rs*gv.z + bv.z);
    o.w = f2bf((v.w-mu)*rs*gv.w + bv.w);
    *reinterpret_cast<ushort4*>(&out[(size_t)pix * CC + c0]) = o;
}

// 3x3 depthwise conv + bias + LN + GELU; 4 consecutive pixels per wave (tap reuse).
__global__ __launch_bounds__(256) void dwconv_ln_gelu_kernel(
    const unsigned short* __restrict__ xl, const float* __restrict__ wt9,
    const float* __restrict__ cb, const float* __restrict__ lg,
    const float* __restrict__ lb, unsigned short* __restrict__ out)
{
    int bid = blockIdx.x;
    int wg = (bid & 7) * (gridDim.x >> 3) + (bid >> 3);
    int wave = threadIdx.x >> 6, lane = threadIdx.x & 63;
    int pix0 = wg * 16 + wave * 4;
    int n = pix0 / (HH*WWD); int rem = pix0 % (HH*WWD);
    int h = rem / WWD, wb = rem % WWD;             // wb % 4 == 0
    int c0 = lane * 4;

    float4 wv[9];
    #pragma unroll
    for (int t = 0; t < 9; ++t)
        wv[t] = *reinterpret_cast<const float4*>(&wt9[t*256 + c0]);
    float4 cbv = *reinterpret_cast<const float4*>(&cb[c0]);
    float4 gv  = *reinterpret_cast<const float4*>(&lg[c0]);
    float4 bv  = *reinterpret_cast<const float4*>(&lb[c0]);

    float4 a[4];
    #pragma unroll
    for (int px = 0; px < 4; ++px) a[px] = cbv;

    #pragma unroll
    for (int r = 0; r < 3; ++r) {
        int hh = h + r - 1;
        if (hh < 0 || hh >= HH) continue;
        const unsigned short* rowp = xl + (((size_t)n*HH + hh)*WWD)*CC + c0;
        #pragma unroll
        for (int dc = 0; dc < 6; ++dc) {
            int cc = wb - 1 + dc;
            if (cc < 0 || cc >= WWD) continue;
            ushort4 xv = *reinterpret_cast<const ushort4*>(&rowp[(size_t)cc*CC]);
            float fx = bf2f(xv.x), fy = bf2f(xv.y), fz = bf2f(xv.z), fw = bf2f(xv.w);
            #pragma unroll
            for (int px = 0; px < 4; ++px) {
                int kx = dc - px;
                if (kx >= 0 && kx < 3) {
                    float4 wq = wv[r*3 + kx];
                    a[px].x += fx*wq.x; a[px].y += fy*wq.y;
                    a[px].z += fz*wq.z; a[px].w += fw*wq.w;
                }
            }
        }
    }

    #pragma unroll
    for (int px = 0; px < 4; ++px) {
        float s = a[px].x + a[px].y + a[px].z + a[px].w;
        float sq = a[px].x*a[px].x + a[px].y*a[px].y + a[px].z*a[px].z + a[px].w*a[px].w;
        wave_reduce2(s, sq);
        float mu = s*(1.f/256.f), var = sq*(1.f/256.f) - mu*mu;
        float rs = rsqrtf(var + 1e-6f);
        ushort4 o;
        o.x = f2bf(gelu_fast((a[px].x-mu)*rs*gv.x + bv.x));
        o.y = f2bf(gelu_fast((a[px].y-mu)*rs*gv.y + bv.y));
        o.z = f2bf(gelu_fast((a[px].z-mu)*rs*gv.z + bv.z));
        o.w = f2bf(gelu_fast((a[px].w-mu)*rs*gv.w + bv.w));
        *reinterpret_cast<ushort4*>(&out[(size_t)(pix0+px)*CC + c0]) = o;
    }
}

// ------- bf16 MFMA GEMM v4b: 64-row x 256-col tile, wave = 64 rows x 64 cols -------
// A staged in ONE 32 KB LDS chunk; B per-lane direct from L2-resident weights.
// v4b: EPI5's S1/S2 overlaid into the A-tile LDS (dead after K loop) so ALL
// variants use exactly 32 KB -> 5 blocks/CU with __launch_bounds__(256,5).
// EPI 1: bf16 gelu(fast). EPI 2: fp32 extra1+extra2[c]*v. EPI 3: bf16 plain.
// EPI 4: off/msk routing -> bf16. EPI 5: xres + fused LN2 -> y2.
template<int EPI>
__global__ __launch_bounds__(256, 5) void gemm_v4(
    const unsigned short* __restrict__ A, const unsigned short* __restrict__ Bt,
    const float* __restrict__ bias, float* __restrict__ Cf, float* __restrict__ Cf2,
    unsigned short* __restrict__ Cb, int M, int N, int K,
    const float* __restrict__ extra1, const float* __restrict__ extra2,
    const float* __restrict__ lng, const float* __restrict__ lnb)
{
    __shared__ unsigned short Al[16384];   // 32 KB: [kb:32][row:64][8]
    const int tid = threadIdx.x;
    const int wave = tid >> 6, lane = tid & 63;
    const int lm = lane & 15, kq = lane >> 4;

    int bid = blockIdx.x + blockIdx.y * gridDim.x;
    int nwg = gridDim.x * gridDim.y;
    int wg = (bid & 7) * (nwg >> 3) + (bid >> 3);
    const int m0 = (wg / gridDim.x) * 64;
    const int n0 = (wg % gridDim.x) * 256;
    const int n0w = n0 + wave * 64;

    f32x4 acc[4][4];
    #pragma unroll
    for (int i = 0; i < 4; ++i)
        #pragma unroll
        for (int j = 0; j < 4; ++j)
            acc[i][j] = (f32x4){0.f, 0.f, 0.f, 0.f};

    const unsigned short* Bw = Bt + (size_t)(n0w + lm) * K;

    const int nch = K >> 8;
    for (int ch = 0; ch < nch; ++ch) {
        if (ch) __syncthreads();
        int kc = ch << 8;
        #pragma unroll
        for (int jr = 0; jr < 8; ++jr) {
            int idx = jr*256 + tid;
            int kb = idx >> 6, row = idx & 63;
            gl_lds16(A + (size_t)(m0+row)*K + kc + kb*8,
                     (char*)Al + (jr*4 + wave)*1024);
        }
        __syncthreads();
        #pragma unroll
        for (int ks = 0; ks < 8; ++ks) {
            int kb = ks*4 + kq;
            bf16x8 af[4], bf[4];
            #pragma unroll
            for (int mi = 0; mi < 4; ++mi)
                af[mi] = *reinterpret_cast<const bf16x8*>(
                    &Al[(kb*64 + mi*16 + lm)*8]);
            #pragma unroll
            for (int ni = 0; ni < 4; ++ni)
                bf[ni] = *reinterpret_cast<const bf16x8*>(
                    &Bw[(size_t)ni*16*K + kc + ks*32 + kq*8]);
            #pragma unroll
            for (int mi = 0; mi < 4; ++mi)
                #pragma unroll
                for (int ni = 0; ni < 4; ++ni)
                    acc[mi][ni] = __builtin_amdgcn_mfma_f32_16x16x32_bf16(
                        af[mi], bf[ni], acc[mi][ni], 0, 0, 0);
        }
    }

    if (EPI == 5) {
        // S1/S2 overlay into Al (dead after K loop). Barrier first: other waves
        // may still be reading Al's last chunk.
        __syncthreads();
        float* S1 = (float*)Al;          // [4][64]
        float* S2 = (float*)Al + 256;    // [4][64]
        #pragma unroll
        for (int mi = 0; mi < 4; ++mi) {
            #pragma unroll
            for (int j = 0; j < 4; ++j) {
                int r = m0 + mi*16 + kq*4 + j;
                float ps = 0.f, pq = 0.f;
                #pragma unroll
                for (int ni = 0; ni < 4; ++ni) {
                    int c = n0w + ni*16 + lm;
                    float v = acc[mi][ni][j] + bias[c];
                    float xr = extra1[(size_t)r*N + c] + extra2[c]*v;
                    acc[mi][ni][j] = xr;
                    ps += xr; pq += xr*xr;
                }
                #pragma unroll
                for (int o = 8; o >= 1; o >>= 1) {
                    ps += __shfl_xor(ps, o);
                    pq += __shfl_xor(pq, o);
                }
                if (lm == 0) {
                    S1[wave*64 + mi*16 + kq*4 + j] = ps;
                    S2[wave*64 + mi*16 + kq*4 + j] = pq;
                }
            }
        }
        __syncthreads();
        #pragma unroll
        for (int mi = 0; mi < 4; ++mi) {
            #pragma unroll
            for (int j = 0; j < 4; ++j) {
                int rl = mi*16 + kq*4 + j;
                int r = m0 + rl;
                float s = S1[rl] + S1[64+rl] + S1[128+rl] + S1[192+rl];
                float sq = S2[rl] + S2[64+rl] + S2[128+rl] + S2[192+rl];
                float mu = s*(1.f/256.f), var = sq*(1.f/256.f) - mu*mu;
                float rs = rsqrtf(var + 1e-6f);
                #pragma unroll
                for (int ni = 0; ni < 4; ++ni) {
                    int c = n0w + ni*16 + lm;
                    float xr = acc[mi][ni][j];
                    Cf[(size_t)r*N + c] = xr;
                    Cb[(size_t)r*N + c] = f2bf((xr-mu)*rs*lng[c] + lnb[c]);
                }
            }
        }
        return;
    }

    #pragma unroll
    for (int mi = 0; mi < 4; ++mi) {
        #pragma unroll
        for (int ni = 0; ni < 4; ++ni) {
            int c = n0w + ni*16 + lm;
            float bb = bias[c];
            #pragma unroll
            for (int j = 0; j < 4; ++j) {
                int r = m0 + mi*16 + kq*4 + j;
                float v = acc[mi][ni][j] + bb;
                if (EPI == 1) {
                    Cb[(size_t)r*N + c] = f2bf(gelu_fast(v));
                } else if (EPI == 2) {
                    size_t gi = (size_t)r*N + c;
                    Cf[gi] = extra1[gi] + extra2[c]*v;
                } else if (EPI == 3) {
                    Cb[(size_t)r*N + c] = f2bf(v);
                } else if (EPI == 4) {
                    if (c < 288)
                        ((unsigned short*)Cf)[(size_t)r*288 + c] = f2bf(v);
                    else if (c < 432)
                        ((unsigned short*)Cf2)[(size_t)r*144 + (c-288)] = f2bf(v);
                }
            }
        }
    }
}

__device__ __forceinline__ void tap8(const unsigned short* __restrict__ img, int yi, int xi,
                                     float wgt, float* s) {
    if (yi >= 1 && yi <= 56 && xi >= 1 && xi <= 56) {
        u16x8 v = *reinterpret_cast<const u16x8*>(
            &img[(((size_t)(yi-1))*WWD + (xi-1)) * CC]);
        #pragma unroll
        for (int k = 0; k < 8; ++k) s[k] += wgt*bf2f(v[k]);
    }
}

// Deformable sampling + fused 9-way softmax. 2 pixels/wave; lane = (px, g, c8).
__global__ __launch_bounds__(256) void dcn_sample_kernel(
    const unsigned short* __restrict__ xproj, const unsigned short* __restrict__ offs,
    const unsigned short* __restrict__ msk, unsigned short* __restrict__ dcn)
{
    int bid = blockIdx.x;
    int wg = (bid & 7) * (gridDim.x >> 3) + (bid >> 3);
    int wave = threadIdx.x >> 6, lane = threadIdx.x & 63;
    int px = lane >> 5, g = (lane >> 1) & 15, c8 = lane & 1;
    int pix = wg * 8 + wave * 2 + px;
    int n = pix / (HH*WWD); int rem = pix % (HH*WWD);
    int h = rem / WWD, w = rem % WWD;
    const unsigned short* op = offs + (size_t)pix*288 + g*18;
    const unsigned short* mp = msk + (size_t)pix*144 + g*9;
    const unsigned short* img = xproj + (size_t)n*(HH*WWD*CC) + g*16 + c8*8;

    float mv[9]; float mx = -1e30f;
    #pragma unroll
    for (int j = 0; j < 9; ++j) { mv[j] = bf2f(mp[j]); mx = fmaxf(mx, mv[j]); }
    float ssum = 0.f;
    #pragma unroll
    for (int j = 0; j < 9; ++j) { mv[j] = __expf(mv[j]-mx); ssum += mv[j]; }
    float minv = __fdividef(1.f, ssum);

    float acc[8] = {0.f,0.f,0.f,0.f,0.f,0.f,0.f,0.f};
    #pragma unroll
    for (int p = 0; p < 9; ++p) {
        ushort2 o2 = *reinterpret_cast<const ushort2*>(&op[p*2]);
        float ox = bf2f(o2.x), oy = bf2f(o2.y);
        float xs = (float)(w + p/3) + ox;   // padded-image coords
        float ys = (float)(h + p%3) + oy;
        float x0f = floorf(xs), y0f = floorf(ys);
        float lx = xs - x0f, ly = ys - y0f;
        int x0 = (int)x0f, y0 = (int)y0f;
        float s[8] = {0.f,0.f,0.f,0.f,0.f,0.f,0.f,0.f};
        tap8(img, y0,   x0,   (1.f-lx)*(1.f-ly), s);
        tap8(img, y0,   x0+1, lx*(1.f-ly),       s);
        tap8(img, y0+1, x0,   (1.f-lx)*ly,       s);
        tap8(img, y0+1, x0+1, lx*ly,             s);
        float m = mv[p]*minv;
        #pragma unroll
        for (int k = 0; k < 8; ++k) acc[k] += m*s[k];
    }
    u16x8 o;
    #pragma unroll
    for (int k = 0; k < 8; ++k) o[k] = f2bf(acc[k]);
    *reinterpret_cast<u16x8*>(&dcn[(size_t)pix*CC + g*16 + c8*8]) = o;
}

extern "C" void kernel_launch(void* const* d_in, const int* in_sizes, int n_in,
                              void* d_out, int out_size, void* d_ws, size_t ws_size,
                              hipStream_t stream)
{
    const float* x    = (const float*)d_in[0];
    const float* n1g  = (const float*)d_in[1];
    const float* n1b  = (const float*)d_in[2];
    const float* n2g  = (const float*)d_in[3];
    const float* n2b  = (const float*)d_in[4];
    const float* g1   = (const float*)d_in[5];
    const float* g2   = (const float*)d_in[6];
    const float* dww  = (const float*)d_in[7];
    const float* dwb  = (const float*)d_in[8];
    const float* dlng = (const float*)d_in[9];
    const float* dlnb = (const float*)d_in[10];
    const float* offw = (const float*)d_in[11];
    const float* offb = (const float*)d_in[12];
    const float* mskw = (const float*)d_in[13];
    const float* mskb = (const float*)d_in[14];
    const float* inw  = (const float*)d_in[15];
    const float* inb  = (const float*)d_in[16];
    const float* outw = (const float*)d_in[17];
    const float* outb = (const float*)d_in[18];
    const float* f1w  = (const float*)d_in[19];
    const float* f1b  = (const float*)d_in[20];
    const float* f2w  = (const float*)d_in[21];
    const float* f2b  = (const float*)d_in[22];
    float* out = (float*)d_out;

    char* base = (char*)d_ws;
    unsigned short* xl_bf    = (unsigned short*)(base + 0);          // 12,845,056 B
    unsigned short* xproj_bf = (unsigned short*)(base + 12845056);   // 12,845,056 B
    float*          xres     = (float*)(base + 25690112);            // 25,690,112 B
    unsigned short* x1_bf    = (unsigned short*)(base + 51380224);   // 12,845,056 B
    unsigned short* offs_bf  = (unsigned short*)(base + 64225280);   // 14,450,688 B
    unsigned short* msk_bf   = (unsigned short*)(base + 78675968);   //  7,225,344 B
    unsigned short* dcn_bf   = xl_bf;                                 // reuse region A
    unsigned short* y2_bf    = x1_bf;                                 // reuse region C
    unsigned short* h1       = (unsigned short*)(base + 64225280 + 21676032); // 51,380,224 B
    unsigned short* btb      = (unsigned short*)(base + 64225280 + 21676032 + 51380224);
    unsigned short* bt_in  = btb + 0;          // 256x256
    unsigned short* bt_om  = btb + 65536;      // 512x256
    unsigned short* bt_out = btb + 196608;     // 256x256
    unsigned short* bt_fc1 = btb + 262144;     // 1024x256
    unsigned short* bt_fc2 = btb + 524288;     // 256x1024
    float*          wt9     = (float*)(btb + 786432);   // 9x256 fp32
    float*          bias_om = (float*)(btb + 805888);   // 512 floats

    // 0. prep: all weight transforms
    prep_kernel<<<3084, 256, 0, stream>>>(inw, offw, offb, mskw, mskb, outw,
        f1w, f2w, dww, bt_in, bt_om, bt_out, bt_fc1, bt_fc2, wt9, bias_om);

    // 1. LN1 -> xl (bf16)
    ln_bf_kernel<<<PIX/4, 256, 0, stream>>>(x, n1g, n1b, xl_bf);
    // 2. in_proj -> xproj (bf16)
    gemm_v4<3><<<dim3(1,392), 256, 0, stream>>>(xl_bf, bt_in, inb, nullptr, nullptr,
        xproj_bf, PIX, 256, 256, nullptr, nullptr, nullptr, nullptr);
    // 3. depthwise conv + LN + GELU -> x1 (bf16)
    dwconv_ln_gelu_kernel<<<PIX/16, 256, 0, stream>>>(xl_bf, wt9, dwb, dlng, dlnb, x1_bf);
    // 4. fused offset+mask GEMM (bf16 routed; msk = raw logits)
    gemm_v4<4><<<dim3(2,392), 256, 0, stream>>>(x1_bf, bt_om, bias_om,
        (float*)offs_bf, (float*)msk_bf, nullptr, PIX, 512, 256,
        nullptr, nullptr, nullptr, nullptr);
    // 5. deformable sampling + fused softmax -> dcn (bf16, 2 px/wave)
    dcn_sample_kernel<<<PIX/8, 256, 0, stream>>>(xproj_bf, offs_bf, msk_bf, dcn_bf);
    // 6. out_proj + residual + fused LN2: xres (fp32) + y2 (bf16)
    gemm_v4<5><<<dim3(1,392), 256, 0, stream>>>(dcn_bf, bt_out, outb, xres, nullptr,
        y2_bf, PIX, 256, 256, x, g1, n2g, n2b);
    // 7. fc1 + gelu -> h1 (bf16)
    gemm_v4<1><<<dim3(4,392), 256, 0, stream>>>(y2_bf, bt_fc1, f1b, nullptr, nullptr,
        h1, PIX, 1024, 256, nullptr, nullptr, nullptr, nullptr);
    // 8. fc2 + residual -> out (fp32), K=1024 in 4 chunks
    gemm_v4<2><<<dim3(1,392), 256, 0, stream>>>(h1, bt_fc2, f2b, out, nullptr,
        nullptr, PIX, 256, 1024, xres, g2, nullptr, nullptr);
}

// Round 19
// 233.022 us; speedup vs baseline: 1.4318x; 1.4318x over previous
//
#include <hip/hip_runtime.h>
#include <math.h>

#define NB 8
#define HH 56
#define WWD 56
#define CC 256
#define PIX (NB*HH*WWD)   // 25088

typedef __attribute__((ext_vector_type(8))) short bf16x8;
typedef __attribute__((ext_vector_type(8))) unsigned short u16x8;
typedef __attribute__((ext_vector_type(4))) float f32x4;

// tanh-form GELU: x*sigmoid(1.5957691x + 0.0713555x^3); native exp/rcp.
__device__ __forceinline__ float gelu_fast(float x) {
    float z = x * fmaf(0.0713554668f, x*x, 1.5957691216f);
    return x * __fdividef(1.0f, 1.0f + __expf(-z));
}
__device__ __forceinline__ unsigned short f2bf(float f) {
    unsigned u = __float_as_uint(f);
    unsigned r = (u + 0x7fffu + ((u >> 16) & 1u)) >> 16;
    return (unsigned short)r;
}
__device__ __forceinline__ float bf2f(unsigned short b) {
    return __uint_as_float(((unsigned)b) << 16);
}
__device__ __forceinline__ void gl_lds16(const void* g, void* l) {
    __builtin_amdgcn_global_load_lds(
        (const __attribute__((address_space(1))) void*)g,
        (__attribute__((address_space(3))) void*)l, 16, 0, 0);
}
__device__ __forceinline__ void wave_reduce2(float& s, float& sq) {
    #pragma unroll
    for (int o = 32; o >= 1; o >>= 1) {
        s  += __shfl_xor(s, o);
        sq += __shfl_xor(sq, o);
    }
}

// ---- one prep kernel: weight transposes (fp32 -> bf16 N-major) + dwconv wt ----
__global__ __launch_bounds__(256) void prep_kernel(
    const float* __restrict__ inw, const float* __restrict__ offw,
    const float* __restrict__ offb, const float* __restrict__ mskw,
    const float* __restrict__ mskb, const float* __restrict__ outw,
    const float* __restrict__ f1w, const float* __restrict__ f2w,
    const float* __restrict__ dww,
    unsigned short* __restrict__ bt_in, unsigned short* __restrict__ bt_om,
    unsigned short* __restrict__ bt_out, unsigned short* __restrict__ bt_fc1,
    unsigned short* __restrict__ bt_fc2, float* __restrict__ wt9,
    float* __restrict__ bias_om)
{
    int i = blockIdx.x * 256 + threadIdx.x;
    if (i < 65536) {
        int n = i >> 8, k = i & 255;
        bt_in[i] = f2bf(inw[(size_t)k*256 + n]);
    } else if (i < 196608) {
        int j = i - 65536;
        int n = j >> 8, k = j & 255;
        float v = (n < 288) ? offw[(size_t)k*288 + n]
                : (n < 432) ? mskw[(size_t)k*144 + (n-288)] : 0.f;
        bt_om[j] = f2bf(v);
    } else if (i < 262144) {
        int j = i - 196608;
        int n = j >> 8, k = j & 255;
        bt_out[j] = f2bf(outw[(size_t)k*256 + n]);
    } else if (i < 524288) {
        int j = i - 262144;
        int n = j >> 8, k = j & 255;
        bt_fc1[j] = f2bf(f1w[(size_t)k*1024 + n]);
    } else if (i < 786432) {
        int j = i - 524288;
        int n = j >> 10, k = j & 1023;
        bt_fc2[j] = f2bf(f2w[(size_t)k*256 + n]);
    } else if (i < 788736) {
        int j = i - 786432;
        int t = j >> 8, c = j & 255;
        wt9[j] = dww[(size_t)c*9 + t];
    } else if (i < 789248) {
        int j = i - 788736;
        bias_om[j] = (j < 288) ? offb[j] : (j < 432) ? mskb[j-288] : 0.f;
    }
}

// LayerNorm over C=256, fp32 in -> bf16 out. One wave/pixel.
__global__ __launch_bounds__(256) void ln_bf_kernel(
    const float* __restrict__ in, const float* __restrict__ g,
    const float* __restrict__ b, unsigned short* __restrict__ out)
{
    int wave = threadIdx.x >> 6, lane = threadIdx.x & 63;
    int pix = blockIdx.x * 4 + wave;
    int c0 = lane * 4;
    float4 v = *reinterpret_cast<const float4*>(&in[(size_t)pix * CC + c0]);
    float s = v.x + v.y + v.z + v.w;
    float sq = v.x*v.x + v.y*v.y + v.z*v.z + v.w*v.w;
    wave_reduce2(s, sq);
    float mu = s * (1.0f/256.0f);
    float var = sq * (1.0f/256.0f) - mu*mu;
    float rs = rsqrtf(var + 1e-6f);
    float4 gv = *reinterpret_cast<const float4*>(&g[c0]);
    float4 bv = *reinterpret_cast<const float4*>(&b[c0]);
    ushort4 o;
    o.x = f2bf((v.x-mu)*rs*gv.x + bv.x);
    o.y = f2bf((v.y-mu)*rs*gv.y + bv.y);
    o.z = f2bf((v.z-mu)*rs*gv.z + bv.z);
    o.w = f2bf((v.w-mu)*rs*gv.w + bv.w);
    *reinterpret_cast<ushort4*>(&out[(size_t)pix * CC + c0]) = o;
}

// 3x3 depthwise conv + bias + LN + GELU; 4 consecutive pixels per wave (tap reuse).
__global__ __launch_bounds__(256) void dwconv_ln_gelu_kernel(
    const unsigned short* __restrict__ xl, const float* __restrict__ wt9,
    const float* __restrict__ cb, const float* __restrict__ lg,
    const float* __restrict__ lb, unsigned short* __restrict__ out)
{
    int bid = blockIdx.x;
    int wg = (bid & 7) * (gridDim.x >> 3) + (bid >> 3);
    int wave = threadIdx.x >> 6, lane = threadIdx.x & 63;
    int pix0 = wg * 16 + wave * 4;
    int n = pix0 / (HH*WWD); int rem = pix0 % (HH*WWD);
    int h = rem / WWD, wb = rem % WWD;             // wb % 4 == 0
    int c0 = lane * 4;

    float4 wv[9];
    #pragma unroll
    for (int t = 0; t < 9; ++t)
        wv[t] = *reinterpret_cast<const float4*>(&wt9[t*256 + c0]);
    float4 cbv = *reinterpret_cast<const float4*>(&cb[c0]);
    float4 gv  = *reinterpret_cast<const float4*>(&lg[c0]);
    float4 bv  = *reinterpret_cast<const float4*>(&lb[c0]);

    float4 a[4];
    #pragma unroll
    for (int px = 0; px < 4; ++px) a[px] = cbv;

    #pragma unroll
    for (int r = 0; r < 3; ++r) {
        int hh = h + r - 1;
        if (hh < 0 || hh >= HH) continue;
        const unsigned short* rowp = xl + (((size_t)n*HH + hh)*WWD)*CC + c0;
        #pragma unroll
        for (int dc = 0; dc < 6; ++dc) {
            int cc = wb - 1 + dc;
            if (cc < 0 || cc >= WWD) continue;
            ushort4 xv = *reinterpret_cast<const ushort4*>(&rowp[(size_t)cc*CC]);
            float fx = bf2f(xv.x), fy = bf2f(xv.y), fz = bf2f(xv.z), fw = bf2f(xv.w);
            #pragma unroll
            for (int px = 0; px < 4; ++px) {
                int kx = dc - px;
                if (kx >= 0 && kx < 3) {
                    float4 wq = wv[r*3 + kx];
                    a[px].x += fx*wq.x; a[px].y += fy*wq.y;
                    a[px].z += fz*wq.z; a[px].w += fw*wq.w;
                }
            }
        }
    }

    #pragma unroll
    for (int px = 0; px < 4; ++px) {
        float s = a[px].x + a[px].y + a[px].z + a[px].w;
        float sq = a[px].x*a[px].x + a[px].y*a[px].y + a[px].z*a[px].z + a[px].w*a[px].w;
        wave_reduce2(s, sq);
        float mu = s*(1.f/256.f), var = sq*(1.f/256.f) - mu*mu;
        float rs = rsqrtf(var + 1e-6f);
        ushort4 o;
        o.x = f2bf(gelu_fast((a[px].x-mu)*rs*gv.x + bv.x));
        o.y = f2bf(gelu_fast((a[px].y-mu)*rs*gv.y + bv.y));
        o.z = f2bf(gelu_fast((a[px].z-mu)*rs*gv.z + bv.z));
        o.w = f2bf(gelu_fast((a[px].w-mu)*rs*gv.w + bv.w));
        *reinterpret_cast<ushort4*>(&out[(size_t)(pix0+px)*CC + c0]) = o;
    }
}

// ------- bf16 MFMA GEMM v4: 64-row x 256-col tile, wave = 64 rows x 64 cols -------
// A staged in ONE 32 KB LDS chunk; B per-lane direct from L2-resident weights.
// Proven config (233 us, reproduced 3x): runtime K/N, MT=64, separate launches,
// __launch_bounds__(256,4). Falsified levers (do NOT revisit): dbuf pipeline,
// counted vmcnt, MT=32, templated K/N, MLP fusion, launch merge, 5-block
// occupancy (VGPR cap 48 < acc's 64 -> scratch spills, 334 us).
// EPI 1: bf16 gelu(fast). EPI 2: fp32 extra1+extra2[c]*v. EPI 3: bf16 plain.
// EPI 4: off/msk routing -> bf16. EPI 5: xres + fused LN2 -> y2.
template<int EPI>
__global__ __launch_bounds__(256, 4) void gemm_v4(
    const unsigned short* __restrict__ A, const unsigned short* __restrict__ Bt,
    const float* __restrict__ bias, float* __restrict__ Cf, float* __restrict__ Cf2,
    unsigned short* __restrict__ Cb, int M, int N, int K,
    const float* __restrict__ extra1, const float* __restrict__ extra2,
    const float* __restrict__ lng, const float* __restrict__ lnb)
{
    __shared__ unsigned short Al[16384];   // 32 KB: [kb:32][row:64][8]
    __shared__ float S1[4][64], S2[4][64];
    const int tid = threadIdx.x;
    const int wave = tid >> 6, lane = tid & 63;
    const int lm = lane & 15, kq = lane >> 4;

    int bid = blockIdx.x + blockIdx.y * gridDim.x;
    int nwg = gridDim.x * gridDim.y;
    int wg = (bid & 7) * (nwg >> 3) + (bid >> 3);
    const int m0 = (wg / gridDim.x) * 64;
    const int n0 = (wg % gridDim.x) * 256;
    const int n0w = n0 + wave * 64;

    f32x4 acc[4][4];
    #pragma unroll
    for (int i = 0; i < 4; ++i)
        #pragma unroll
        for (int j = 0; j < 4; ++j)
            acc[i][j] = (f32x4){0.f, 0.f, 0.f, 0.f};

    const unsigned short* Bw = Bt + (size_t)(n0w + lm) * K;

    const int nch = K >> 8;
    for (int ch = 0; ch < nch; ++ch) {
        if (ch) __syncthreads();
        int kc = ch << 8;
        #pragma unroll
        for (int jr = 0; jr < 8; ++jr) {
            int idx = jr*256 + tid;
            int kb = idx >> 6, row = idx & 63;
            gl_lds16(A + (size_t)(m0+row)*K + kc + kb*8,
                     (char*)Al + (jr*4 + wave)*1024);
        }
        __syncthreads();
        #pragma unroll
        for (int ks = 0; ks < 8; ++ks) {
            int kb = ks*4 + kq;
            bf16x8 af[4], bf[4];
            #pragma unroll
            for (int mi = 0; mi < 4; ++mi)
                af[mi] = *reinterpret_cast<const bf16x8*>(
                    &Al[(kb*64 + mi*16 + lm)*8]);
            #pragma unroll
            for (int ni = 0; ni < 4; ++ni)
                bf[ni] = *reinterpret_cast<const bf16x8*>(
                    &Bw[(size_t)ni*16*K + kc + ks*32 + kq*8]);
            #pragma unroll
            for (int mi = 0; mi < 4; ++mi)
                #pragma unroll
                for (int ni = 0; ni < 4; ++ni)
                    acc[mi][ni] = __builtin_amdgcn_mfma_f32_16x16x32_bf16(
                        af[mi], bf[ni], acc[mi][ni], 0, 0, 0);
        }
    }

    if (EPI == 5) {
        #pragma unroll
        for (int mi = 0; mi < 4; ++mi) {
            #pragma unroll
            for (int j = 0; j < 4; ++j) {
                int r = m0 + mi*16 + kq*4 + j;
                float ps = 0.f, pq = 0.f;
                #pragma unroll
                for (int ni = 0; ni < 4; ++ni) {
                    int c = n0w + ni*16 + lm;
                    float v = acc[mi][ni][j] + bias[c];
                    float xr = extra1[(size_t)r*N + c] + extra2[c]*v;
                    acc[mi][ni][j] = xr;
                    ps += xr; pq += xr*xr;
                }
                #pragma unroll
                for (int o = 8; o >= 1; o >>= 1) {
                    ps += __shfl_xor(ps, o);
                    pq += __shfl_xor(pq, o);
                }
                if (lm == 0) {
                    S1[wave][mi*16 + kq*4 + j] = ps;
                    S2[wave][mi*16 + kq*4 + j] = pq;
                }
            }
        }
        __syncthreads();
        #pragma unroll
        for (int mi = 0; mi < 4; ++mi) {
            #pragma unroll
            for (int j = 0; j < 4; ++j) {
                int rl = mi*16 + kq*4 + j;
                int r = m0 + rl;
                float s = S1[0][rl] + S1[1][rl] + S1[2][rl] + S1[3][rl];
                float sq = S2[0][rl] + S2[1][rl] + S2[2][rl] + S2[3][rl];
                float mu = s*(1.f/256.f), var = sq*(1.f/256.f) - mu*mu;
                float rs = rsqrtf(var + 1e-6f);
                #pragma unroll
                for (int ni = 0; ni < 4; ++ni) {
                    int c = n0w + ni*16 + lm;
                    float xr = acc[mi][ni][j];
                    Cf[(size_t)r*N + c] = xr;
                    Cb[(size_t)r*N + c] = f2bf((xr-mu)*rs*lng[c] + lnb[c]);
                }
            }
        }
        return;
    }

    #pragma unroll
    for (int mi = 0; mi < 4; ++mi) {
        #pragma unroll
        for (int ni = 0; ni < 4; ++ni) {
            int c = n0w + ni*16 + lm;
            float bb = bias[c];
            #pragma unroll
            for (int j = 0; j < 4; ++j) {
                int r = m0 + mi*16 + kq*4 + j;
                float v = acc[mi][ni][j] + bb;
                if (EPI == 1) {
                    Cb[(size_t)r*N + c] = f2bf(gelu_fast(v));
                } else if (EPI == 2) {
                    size_t gi = (size_t)r*N + c;
                    Cf[gi] = extra1[gi] + extra2[c]*v;
                } else if (EPI == 3) {
                    Cb[(size_t)r*N + c] = f2bf(v);
                } else if (EPI == 4) {
                    if (c < 288)
                        ((unsigned short*)Cf)[(size_t)r*288 + c] = f2bf(v);
                    else if (c < 432)
                        ((unsigned short*)Cf2)[(size_t)r*144 + (c-288)] = f2bf(v);
                }
            }
        }
    }
}

__device__ __forceinline__ void tap8(const unsigned short* __restrict__ img, int yi, int xi,
                                     float wgt, float* s) {
    if (yi >= 1 && yi <= 56 && xi >= 1 && xi <= 56) {
        u16x8 v = *reinterpret_cast<const u16x8*>(
            &img[(((size_t)(yi-1))*WWD + (xi-1)) * CC]);
        #pragma unroll
        for (int k = 0; k < 8; ++k) s[k] += wgt*bf2f(v[k]);
    }
}

// Deformable sampling + fused 9-way softmax. 2 pixels/wave; lane = (px, g, c8).
__global__ __launch_bounds__(256) void dcn_sample_kernel(
    const unsigned short* __restrict__ xproj, const unsigned short* __restrict__ offs,
    const unsigned short* __restrict__ msk, unsigned short* __restrict__ dcn)
{
    int bid = blockIdx.x;
    int wg = (bid & 7) * (gridDim.x >> 3) + (bid >> 3);
    int wave = threadIdx.x >> 6, lane = threadIdx.x & 63;
    int px = lane >> 5, g = (lane >> 1) & 15, c8 = lane & 1;
    int pix = wg * 8 + wave * 2 + px;
    int n = pix / (HH*WWD); int rem = pix % (HH*WWD);
    int h = rem / WWD, w = rem % WWD;
    const unsigned short* op = offs + (size_t)pix*288 + g*18;
    const unsigned short* mp = msk + (size_t)pix*144 + g*9;
    const unsigned short* img = xproj + (size_t)n*(HH*WWD*CC) + g*16 + c8*8;

    float mv[9]; float mx = -1e30f;
    #pragma unroll
    for (int j = 0; j < 9; ++j) { mv[j] = bf2f(mp[j]); mx = fmaxf(mx, mv[j]); }
    float ssum = 0.f;
    #pragma unroll
    for (int j = 0; j < 9; ++j) { mv[j] = __expf(mv[j]-mx); ssum += mv[j]; }
    float minv = __fdividef(1.f, ssum);

    float acc[8] = {0.f,0.f,0.f,0.f,0.f,0.f,0.f,0.f};
    #pragma unroll
    for (int p = 0; p < 9; ++p) {
        ushort2 o2 = *reinterpret_cast<const ushort2*>(&op[p*2]);
        float ox = bf2f(o2.x), oy = bf2f(o2.y);
        float xs = (float)(w + p/3) + ox;   // padded-image coords
        float ys = (float)(h + p%3) + oy;
        float x0f = floorf(xs), y0f = floorf(ys);
        float lx = xs - x0f, ly = ys - y0f;
        int x0 = (int)x0f, y0 = (int)y0f;
        float s[8] = {0.f,0.f,0.f,0.f,0.f,0.f,0.f,0.f};
        tap8(img, y0,   x0,   (1.f-lx)*(1.f-ly), s);
        tap8(img, y0,   x0+1, lx*(1.f-ly),       s);
        tap8(img, y0+1, x0,   (1.f-lx)*ly,       s);
        tap8(img, y0+1, x0+1, lx*ly,             s);
        float m = mv[p]*minv;
        #pragma unroll
        for (int k = 0; k < 8; ++k) acc[k] += m*s[k];
    }
    u16x8 o;
    #pragma unroll
    for (int k = 0; k < 8; ++k) o[k] = f2bf(acc[k]);
    *reinterpret_cast<u16x8*>(&dcn[(size_t)pix*CC + g*16 + c8*8]) = o;
}

extern "C" void kernel_launch(void* const* d_in, const int* in_sizes, int n_in,
                              void* d_out, int out_size, void* d_ws, size_t ws_size,
                              hipStream_t stream)
{
    const float* x    = (const float*)d_in[0];
    const float* n1g  = (const float*)d_in[1];
    const float* n1b  = (const float*)d_in[2];
    const float* n2g  = (const float*)d_in[3];
    const float* n2b  = (const float*)d_in[4];
    const float* g1   = (const float*)d_in[5];
    const float* g2   = (const float*)d_in[6];
    const float* dww  = (const float*)d_in[7];
    const float* dwb  = (const float*)d_in[8];
    const float* dlng = (const float*)d_in[9];
    const float* dlnb = (const float*)d_in[10];
    const float* offw = (const float*)d_in[11];
    const float* offb = (const float*)d_in[12];
    const float* mskw = (const float*)d_in[13];
    const float* mskb = (const float*)d_in[14];
    const float* inw  = (const float*)d_in[15];
    const float* inb  = (const float*)d_in[16];
    const float* outw = (const float*)d_in[17];
    const float* outb = (const float*)d_in[18];
    const float* f1w  = (const float*)d_in[19];
    const float* f1b  = (const float*)d_in[20];
    const float* f2w  = (const float*)d_in[21];
    const float* f2b  = (const float*)d_in[22];
    float* out = (float*)d_out;

    char* base = (char*)d_ws;
    unsigned short* xl_bf    = (unsigned short*)(base + 0);          // 12,845,056 B
    unsigned short* xproj_bf = (unsigned short*)(base + 12845056);   // 12,845,056 B
    float*          xres     = (float*)(base + 25690112);            // 25,690,112 B
    unsigned short* x1_bf    = (unsigned short*)(base + 51380224);   // 12,845,056 B
    unsigned short* offs_bf  = (unsigned short*)(base + 64225280);   // 14,450,688 B
    unsigned short* msk_bf   = (unsigned short*)(base + 78675968);   //  7,225,344 B
    unsigned short* dcn_bf   = xl_bf;                                 // reuse region A
    unsigned short* y2_bf    = x1_bf;                                 // reuse region C
    unsigned short* h1       = (unsigned short*)(base + 64225280 + 21676032); // 51,380,224 B
    unsigned short* btb      = (unsigned short*)(base + 64225280 + 21676032 + 51380224);
    unsigned short* bt_in  = btb + 0;          // 256x256
    unsigned short* bt_om  = btb + 65536;      // 512x256
    unsigned short* bt_out = btb + 196608;     // 256x256
    unsigned short* bt_fc1 = btb + 262144;     // 1024x256
    unsigned short* bt_fc2 = btb + 524288;     // 256x1024
    float*          wt9     = (float*)(btb + 786432);   // 9x256 fp32
    float*          bias_om = (float*)(btb + 805888);   // 512 floats

    // 0. prep: all weight transforms
    prep_kernel<<<3084, 256, 0, stream>>>(inw, offw, offb, mskw, mskb, outw,
        f1w, f2w, dww, bt_in, bt_om, bt_out, bt_fc1, bt_fc2, wt9, bias_om);

    // 1. LN1 -> xl (bf16)
    ln_bf_kernel<<<PIX/4, 256, 0, stream>>>(x, n1g, n1b, xl_bf);
    // 2. in_proj -> xproj (bf16)
    gemm_v4<3><<<dim3(1,392), 256, 0, stream>>>(xl_bf, bt_in, inb, nullptr, nullptr,
        xproj_bf, PIX, 256, 256, nullptr, nullptr, nullptr, nullptr);
    // 3. depthwise conv + LN + GELU -> x1 (bf16)
    dwconv_ln_gelu_kernel<<<PIX/16, 256, 0, stream>>>(xl_bf, wt9, dwb, dlng, dlnb, x1_bf);
    // 4. fused offset+mask GEMM (bf16 routed; msk = raw logits)
    gemm_v4<4><<<dim3(2,392), 256, 0, stream>>>(x1_bf, bt_om, bias_om,
        (float*)offs_bf, (float*)msk_bf, nullptr, PIX, 512, 256,
        nullptr, nullptr, nullptr, nullptr);
    // 5. deformable sampling + fused softmax -> dcn (bf16, 2 px/wave)
    dcn_sample_kernel<<<PIX/8, 256, 0, stream>>>(xproj_bf, offs_bf, msk_bf, dcn_bf);
    // 6. out_proj + residual + fused LN2: xres (fp32) + y2 (bf16)
    gemm_v4<5><<<dim3(1,392), 256, 0, stream>>>(dcn_bf, bt_out, outb, xres, nullptr,
        y2_bf, PIX, 256, 256, x, g1, n2g, n2b);
    // 7. fc1 + gelu -> h1 (bf16)
    gemm_v4<1><<<dim3(4,392), 256, 0, stream>>>(y2_bf, bt_fc1, f1b, nullptr, nullptr,
        h1, PIX, 1024, 256, nullptr, nullptr, nullptr, nullptr);
    // 8. fc2 + residual -> out (fp32), K=1024 in 4 chunks
    gemm_v4<2><<<dim3(1,392), 256, 0, stream>>>(h1, bt_fc2, f2b, out, nullptr,
        nullptr, PIX, 256, 1024, xres, g2, nullptr, nullptr);
}